// Round 1
// 392.924 us; speedup vs baseline: 1.0132x; 1.0132x over previous
//
#include <hip/hip_runtime.h>
#include <hip/hip_bf16.h>
#include <math.h>

// Node classifier: KProp(K=2, gcn_norm) -> SAGEConv(64->64)+selu -> SAGEConv(64->40) -> softmax
// N=100000, E=1600000, D=H=64, C=40.
//
// R13 = R12 with prop_softmax restructured for wide gathers:
//   t2 rows (40 bf16 = 80B) gathered as 10x ushort4 by lanes l<10 of 4 edge
//   slots (g = lane>>4), instead of 64x 2B loads reading 128B/row.
//   4 VMEM instrs per 16 edges (was 16), exact-row reads, float4 epilogue.

#define RFL(x) __builtin_amdgcn_readfirstlane(x)
#define BK_SHIFT 10        // coarse bucket = dst>>10 (1024 nodes)
#define MAXBUCK 256

__device__ __forceinline__ float bf2f(unsigned short u) {
    return __uint_as_float((unsigned)u << 16);
}
__device__ __forceinline__ unsigned short f2bf(float f) {
    __hip_bfloat16 b = __float2bfloat16(f);   // RTN
    return *reinterpret_cast<unsigned short*>(&b);
}

// ---------------- CSR build ----------------

__global__ void init_bcursor_kernel(int* __restrict__ bcursor, int nbuck, int cap) {
    int i = blockIdx.x * blockDim.x + threadIdx.x;
    if (i < nbuck) bcursor[i] = i * cap;
}

// Phase 1: block-private coarse bucket partition; packed u32 (src<<10 | dst&1023).
__global__ __launch_bounds__(256) void partition_kernel(const int* __restrict__ src,
                                                        const int* __restrict__ dst,
                                                        int* __restrict__ bcursor,
                                                        unsigned int* __restrict__ temp,
                                                        int e, int nbuck, int cap) {
    __shared__ int bc[MAXBUCK];
    int t = threadIdx.x;
    int chunk = (e + gridDim.x - 1) / gridDim.x;
    int base = blockIdx.x * chunk;
    int cnt = e - base;
    if (cnt > chunk) cnt = chunk;
    if (cnt < 0) cnt = 0;
    for (int j = t; j < nbuck; j += 256) bc[j] = 0;
    __syncthreads();
    for (int i = t; i < cnt; i += 256) {
        int d = dst[base + i];
        atomicAdd(&bc[d >> BK_SHIFT], 1);
    }
    __syncthreads();
    for (int j = t; j < nbuck; j += 256) {
        int c = bc[j];
        bc[j] = (c > 0) ? atomicAdd(&bcursor[j], c) : 0;
    }
    __syncthreads();
    for (int i = t; i < cnt; i += 256) {
        int s = src[base + i];
        int d = dst[base + i];
        int bk = d >> BK_SHIFT;
        int p = atomicAdd(&bc[bk], 1);
        if (p < (bk + 1) * cap) temp[p] = ((unsigned int)s << BK_SHIFT) | (unsigned int)(d & 1023);
    }
}

// Phase 2: per-bucket counting sort by node_local + deg/dis/cnt_inv/row_ptr.
__global__ __launch_bounds__(256) void bucket_csr_kernel(const unsigned int* __restrict__ temp,
                                                         const int* __restrict__ bcursor,
                                                         int* __restrict__ row_ptr,
                                                         float* __restrict__ dis,
                                                         float* __restrict__ cnt_inv,
                                                         int* __restrict__ csr_src,
                                                         int n, int cap, int nbuck, int e) {
    __shared__ int cnt3[1024];
    __shared__ int part[256];
    int b = blockIdx.x;
    int t = threadIdx.x;
    int nbeg = b << BK_SHIFT;
    int cj = 0;
    if (t < nbuck) {
        cj = bcursor[t] - t * cap;
        if (cj > cap) cj = cap;
    }
    part[t] = cj;
    __syncthreads();
    for (int off = 1; off < 256; off <<= 1) {
        int u = (t >= off) ? part[t - off] : 0;
        __syncthreads();
        part[t] += u;
        __syncthreads();
    }
    int cntb = bcursor[b] - b * cap;
    if (cntb > cap) cntb = cap;
    int bbase = part[b] - cntb;
    __syncthreads();
    for (int i = t; i < 1024; i += 256) cnt3[i] = 0;
    __syncthreads();
    const unsigned int* tb = temp + (size_t)b * cap;
    for (int i = t; i < cntb; i += 256) {
        atomicAdd(&cnt3[tb[i] & 1023u], 1);
    }
    __syncthreads();
    int d0 = cnt3[t * 4 + 0], d1 = cnt3[t * 4 + 1], d2 = cnt3[t * 4 + 2], d3 = cnt3[t * 4 + 3];
    int run = d0 + d1 + d2 + d3;
    int dd[4] = {d0, d1, d2, d3};
#pragma unroll
    for (int k = 0; k < 4; ++k) {
        int node = nbeg + t * 4 + k;
        if (node < n) {
            float fd = (float)dd[k];
            dis[node] = (dd[k] > 0) ? rsqrtf(fd) : 0.0f;
            cnt_inv[node] = 1.0f / fmaxf(fd, 1.0f);
        }
    }
    __syncthreads();
    part[t] = run;
    __syncthreads();
    for (int off = 1; off < 256; off <<= 1) {
        int u = (t >= off) ? part[t - off] : 0;
        __syncthreads();
        part[t] += u;
        __syncthreads();
    }
    int ex = part[t] - run;
    int oo[4];
    oo[0] = ex; oo[1] = ex + d0; oo[2] = ex + d0 + d1; oo[3] = ex + d0 + d1 + d2;
#pragma unroll
    for (int k = 0; k < 4; ++k) {
        cnt3[t * 4 + k] = oo[k];
        int node = nbeg + t * 4 + k;
        if (node < n) row_ptr[node] = bbase + oo[k];
    }
    if (b == nbuck - 1 && t == 0) row_ptr[n] = e;
    __syncthreads();
    for (int i = t; i < cntb; i += 256) {
        unsigned int ed = tb[i];
        int pos = atomicAdd(&cnt3[ed & 1023u], 1);
        csr_src[bbase + pos] = (int)(ed >> BK_SHIFT);
    }
}

// ---------------- fp32 -> bf16 convert ----------------
__global__ void f2bf_kernel(const float4* __restrict__ in, ushort4* __restrict__ out, int n4) {
    int i = blockIdx.x * blockDim.x + threadIdx.x;
    if (i < n4) {
        float4 v = in[i];
        ushort4 u;
        u.x = f2bf(v.x); u.y = f2bf(v.y); u.z = f2bf(v.z); u.w = f2bf(v.w);
        out[i] = u;
    }
}

// ---------------- KProp propagation over bf16 rows (128B), bf16 out ----------------
// Wave per node. lane = g*16 + l: edge slot g (0..3), feature quad l (0..15).
template <int TAG>
__global__ __launch_bounds__(256) void prop4bf_kernel(const ushort4* __restrict__ in4u,
                                                      ushort4* __restrict__ out4u,
                                                      const int* __restrict__ row_ptr,
                                                      const int* __restrict__ csr_src,
                                                      const float* __restrict__ dis,
                                                      int n) {
    int lane = threadIdx.x & 63;
    int g = lane >> 4;
    int l = lane & 15;
    int node = RFL(blockIdx.x * 4 + (threadIdx.x >> 6));
    if (node >= n) return;
    int beg = row_ptr[node];
    int end = row_ptr[node + 1];
    float4 acc = make_float4(0.f, 0.f, 0.f, 0.f);
    int j = beg;
    for (; j + 16 <= end; j += 16) {
        int s[4];
        ushort4 u[4];
        float w[4];
#pragma unroll
        for (int q = 0; q < 4; ++q) s[q] = csr_src[j + q * 4 + g];
#pragma unroll
        for (int q = 0; q < 4; ++q) u[q] = in4u[(size_t)s[q] * 16 + l];
#pragma unroll
        for (int q = 0; q < 4; ++q) w[q] = dis[s[q]];
#pragma unroll
        for (int q = 0; q < 4; ++q) {
            acc.x += w[q] * bf2f(u[q].x);
            acc.y += w[q] * bf2f(u[q].y);
            acc.z += w[q] * bf2f(u[q].z);
            acc.w += w[q] * bf2f(u[q].w);
        }
    }
    for (; j + 8 <= end; j += 8) {
        int s[2];
        ushort4 u[2];
        float w[2];
#pragma unroll
        for (int q = 0; q < 2; ++q) s[q] = csr_src[j + q * 4 + g];
#pragma unroll
        for (int q = 0; q < 2; ++q) u[q] = in4u[(size_t)s[q] * 16 + l];
#pragma unroll
        for (int q = 0; q < 2; ++q) w[q] = dis[s[q]];
#pragma unroll
        for (int q = 0; q < 2; ++q) {
            acc.x += w[q] * bf2f(u[q].x);
            acc.y += w[q] * bf2f(u[q].y);
            acc.z += w[q] * bf2f(u[q].z);
            acc.w += w[q] * bf2f(u[q].w);
        }
    }
    for (; j < end; j += 4) {
        int idx = j + g;
        bool valid = idx < end;
        int s = csr_src[valid ? idx : (end - 1)];
        float w = valid ? dis[s] : 0.0f;
        ushort4 u = in4u[(size_t)s * 16 + l];
        acc.x += w * bf2f(u.x);
        acc.y += w * bf2f(u.y);
        acc.z += w * bf2f(u.z);
        acc.w += w * bf2f(u.w);
    }
    acc.x += __shfl_xor(acc.x, 16); acc.x += __shfl_xor(acc.x, 32);
    acc.y += __shfl_xor(acc.y, 16); acc.y += __shfl_xor(acc.y, 32);
    acc.z += __shfl_xor(acc.z, 16); acc.z += __shfl_xor(acc.z, 32);
    acc.w += __shfl_xor(acc.w, 16); acc.w += __shfl_xor(acc.w, 32);
    if (g == 0) {
        float sc = dis[node];
        ushort4 o;
        o.x = f2bf(acc.x * sc);
        o.y = f2bf(acc.y * sc);
        o.z = f2bf(acc.z * sc);
        o.w = f2bf(acc.w * sc);
        out4u[(size_t)node * 16 + l] = o;
    }
}

// ---------------- mean-agg over bf16 t1 + selu epilogue, bf16 out ----------------
__global__ __launch_bounds__(256) void prop_mean_bf_kernel(const ushort4* __restrict__ in4u,
                                                           ushort4* __restrict__ out4u,
                                                           const int* __restrict__ row_ptr,
                                                           const int* __restrict__ csr_src,
                                                           const float* __restrict__ cnt_inv,
                                                           const float4* __restrict__ r4,
                                                           const float4* __restrict__ b4,
                                                           int n) {
    int lane = threadIdx.x & 63;
    int g = lane >> 4;
    int l = lane & 15;
    int node = RFL(blockIdx.x * 4 + (threadIdx.x >> 6));
    if (node >= n) return;
    int beg = row_ptr[node];
    int end = row_ptr[node + 1];
    float4 acc = make_float4(0.f, 0.f, 0.f, 0.f);
    int j = beg;
    for (; j + 16 <= end; j += 16) {
        int s[4];
        ushort4 u[4];
#pragma unroll
        for (int q = 0; q < 4; ++q) s[q] = csr_src[j + q * 4 + g];
#pragma unroll
        for (int q = 0; q < 4; ++q) u[q] = in4u[(size_t)s[q] * 16 + l];
#pragma unroll
        for (int q = 0; q < 4; ++q) {
            acc.x += bf2f(u[q].x);
            acc.y += bf2f(u[q].y);
            acc.z += bf2f(u[q].z);
            acc.w += bf2f(u[q].w);
        }
    }
    for (; j + 8 <= end; j += 8) {
        int s[2];
        ushort4 u[2];
#pragma unroll
        for (int q = 0; q < 2; ++q) s[q] = csr_src[j + q * 4 + g];
#pragma unroll
        for (int q = 0; q < 2; ++q) u[q] = in4u[(size_t)s[q] * 16 + l];
#pragma unroll
        for (int q = 0; q < 2; ++q) {
            acc.x += bf2f(u[q].x);
            acc.y += bf2f(u[q].y);
            acc.z += bf2f(u[q].z);
            acc.w += bf2f(u[q].w);
        }
    }
    for (; j < end; j += 4) {
        int idx = j + g;
        bool valid = idx < end;
        int s = csr_src[valid ? idx : (end - 1)];
        float w = valid ? 1.0f : 0.0f;
        ushort4 u = in4u[(size_t)s * 16 + l];
        acc.x += w * bf2f(u.x);
        acc.y += w * bf2f(u.y);
        acc.z += w * bf2f(u.z);
        acc.w += w * bf2f(u.w);
    }
    acc.x += __shfl_xor(acc.x, 16); acc.x += __shfl_xor(acc.x, 32);
    acc.y += __shfl_xor(acc.y, 16); acc.y += __shfl_xor(acc.y, 32);
    acc.z += __shfl_xor(acc.z, 16); acc.z += __shfl_xor(acc.z, 32);
    acc.w += __shfl_xor(acc.w, 16); acc.w += __shfl_xor(acc.w, 32);
    if (g == 0) {
        float sc = cnt_inv[node];
        float4 ra = r4[(size_t)node * 16 + l];
        float4 bb = b4[l];
        const float scale = 1.0507009873554805f;
        const float alpha = 1.6732632423543772f;
        float t0 = acc.x * sc + ra.x + bb.x;
        float t1 = acc.y * sc + ra.y + bb.y;
        float t2 = acc.z * sc + ra.z + bb.z;
        float t3 = acc.w * sc + ra.w + bb.w;
        t0 = scale * (t0 > 0.0f ? t0 : alpha * expm1f(t0));
        t1 = scale * (t1 > 0.0f ? t1 : alpha * expm1f(t1));
        t2 = scale * (t2 > 0.0f ? t2 : alpha * expm1f(t2));
        t3 = scale * (t3 > 0.0f ? t3 : alpha * expm1f(t3));
        ushort4 o;
        o.x = f2bf(t0); o.y = f2bf(t1); o.z = f2bf(t2); o.w = f2bf(t3);
        out4u[(size_t)node * 16 + l] = o;
    }
}

// ---------------- 40-wide softmax prop over bf16 t2 (ushort4 gathers) ----------------
// Wave per node. lane = g*16 + l: edge slot g (0..3), feature quad l (0..15, active l<10).
// t2 row = 40 bf16 = 10 ushort4 = 80B, read exactly.
__global__ __launch_bounds__(256) void prop_softmax_bf_kernel(const ushort4* __restrict__ in4u,
                                                              float* __restrict__ out,
                                                              const int* __restrict__ row_ptr,
                                                              const int* __restrict__ csr_src,
                                                              const float* __restrict__ cnt_inv,
                                                              const float* __restrict__ r_add,
                                                              int n) {
    int lane = threadIdx.x & 63;
    int g = lane >> 4;
    int l = lane & 15;
    bool act = l < 10;
    int node = RFL(blockIdx.x * 4 + (threadIdx.x >> 6));
    if (node >= n) return;
    int beg = row_ptr[node];
    int end = row_ptr[node + 1];
    float4 acc = make_float4(0.f, 0.f, 0.f, 0.f);
    const ushort4 uz = make_ushort4(0, 0, 0, 0);
    int j = beg;
    for (; j + 16 <= end; j += 16) {
        int s[4];
        ushort4 u[4] = {uz, uz, uz, uz};
#pragma unroll
        for (int q = 0; q < 4; ++q) s[q] = csr_src[j + q * 4 + g];
        if (act) {
#pragma unroll
            for (int q = 0; q < 4; ++q) u[q] = in4u[(size_t)s[q] * 10 + l];
        }
#pragma unroll
        for (int q = 0; q < 4; ++q) {
            acc.x += bf2f(u[q].x);
            acc.y += bf2f(u[q].y);
            acc.z += bf2f(u[q].z);
            acc.w += bf2f(u[q].w);
        }
    }
    for (; j + 8 <= end; j += 8) {
        int s[2];
        ushort4 u[2] = {uz, uz};
#pragma unroll
        for (int q = 0; q < 2; ++q) s[q] = csr_src[j + q * 4 + g];
        if (act) {
#pragma unroll
            for (int q = 0; q < 2; ++q) u[q] = in4u[(size_t)s[q] * 10 + l];
        }
#pragma unroll
        for (int q = 0; q < 2; ++q) {
            acc.x += bf2f(u[q].x);
            acc.y += bf2f(u[q].y);
            acc.z += bf2f(u[q].z);
            acc.w += bf2f(u[q].w);
        }
    }
    for (; j < end; j += 4) {
        int idx = j + g;
        bool valid = idx < end;
        int s = csr_src[valid ? idx : (end - 1)];
        if (act) {
            ushort4 u = in4u[(size_t)s * 10 + l];
            float w = valid ? 1.0f : 0.0f;
            acc.x += w * bf2f(u.x);
            acc.y += w * bf2f(u.y);
            acc.z += w * bf2f(u.z);
            acc.w += w * bf2f(u.w);
        }
    }
    acc.x += __shfl_xor(acc.x, 16); acc.x += __shfl_xor(acc.x, 32);
    acc.y += __shfl_xor(acc.y, 16); acc.y += __shfl_xor(acc.y, 32);
    acc.z += __shfl_xor(acc.z, 16); acc.z += __shfl_xor(acc.z, 32);
    acc.w += __shfl_xor(acc.w, 16); acc.w += __shfl_xor(acc.w, 32);
    if (g == 0) {
        float sc = cnt_inv[node];
        float4 ra = act ? reinterpret_cast<const float4*>(r_add)[(size_t)node * 10 + l]
                        : make_float4(0.f, 0.f, 0.f, 0.f);
        float t0 = acc.x * sc + ra.x;
        float t1 = acc.y * sc + ra.y;
        float t2 = acc.z * sc + ra.z;
        float t3 = acc.w * sc + ra.w;
        float m = act ? fmaxf(fmaxf(t0, t1), fmaxf(t2, t3)) : -INFINITY;
        m = fmaxf(m, __shfl_xor(m, 1));
        m = fmaxf(m, __shfl_xor(m, 2));
        m = fmaxf(m, __shfl_xor(m, 4));
        m = fmaxf(m, __shfl_xor(m, 8));
        float e0 = act ? __expf(t0 - m) : 0.0f;
        float e1 = act ? __expf(t1 - m) : 0.0f;
        float e2 = act ? __expf(t2 - m) : 0.0f;
        float e3 = act ? __expf(t3 - m) : 0.0f;
        float s = e0 + e1 + e2 + e3;
        s += __shfl_xor(s, 1);
        s += __shfl_xor(s, 2);
        s += __shfl_xor(s, 4);
        s += __shfl_xor(s, 8);
        if (act) {
            float inv = 1.0f / s;
            float4 o;
            o.x = e0 * inv; o.y = e1 * inv; o.z = e2 * inv; o.w = e3 * inv;
            reinterpret_cast<float4*>(out)[(size_t)node * 10 + l] = o;
        }
    }
}

// ---------------- tiled GEMM: [outL(bf16)|outR(fp32)] = in_bf16(64) @ [Wl|Wr] ----------------
template <int OC, int CP>
__global__ __launch_bounds__(256) void gemm_kernel(const unsigned short* __restrict__ in,
                                                   const float* __restrict__ Wl,
                                                   const float* __restrict__ Wr,
                                                   const float* __restrict__ bias,
                                                   __hip_bfloat16* __restrict__ outL,
                                                   float* __restrict__ outR,
                                                   int n, int add_bias) {
    constexpr int HC = OC / 2;
    constexpr int TX = OC / CP;
    constexpr int TY = 256 / TX;
    constexpr int NPT = 64 / TY;
    constexpr int XP = 68;
    constexpr int WP = OC + 4;
    __shared__ float sXT[64 * XP];
    __shared__ float sW[64 * WP];
    int t = threadIdx.x;
    int blk = blockIdx.x;
    for (int i = 0; i < 16; ++i) {
        int idx = i * 256 + t;
        int nd = idx >> 6;
        int k = idx & 63;
        int ng = blk * 64 + nd;
        float v = bf2f(in[(size_t)(ng < n ? ng : n - 1) * 64 + k]);
        sXT[k * XP + nd] = v;
    }
    for (int i = t; i < 64 * HC; i += 256) {
        int k = i / HC;
        int c = i % HC;
        sW[k * WP + c] = Wl[i];
        sW[k * WP + HC + c] = Wr[i];
    }
    __syncthreads();
    int tx = t % TX;
    int ty = t / TX;
    float acc[NPT][CP];
#pragma unroll
    for (int i = 0; i < NPT; ++i)
#pragma unroll
        for (int c = 0; c < CP; ++c) acc[i][c] = 0.0f;
#pragma unroll 4
    for (int k = 0; k < 64; ++k) {
        float xv[NPT];
#pragma unroll
        for (int i = 0; i < NPT; ++i) xv[i] = sXT[k * XP + ty * NPT + i];
        float wv[CP];
#pragma unroll
        for (int c = 0; c < CP; ++c) wv[c] = sW[k * WP + tx + TX * c];
#pragma unroll
        for (int i = 0; i < NPT; ++i)
#pragma unroll
            for (int c = 0; c < CP; ++c) acc[i][c] += xv[i] * wv[c];
    }
#pragma unroll
    for (int i = 0; i < NPT; ++i) {
        int ng = blk * 64 + ty * NPT + i;
        if (ng >= n) break;
#pragma unroll
        for (int c = 0; c < CP; ++c) {
            int col = tx + TX * c;
            if (col < HC) {
                outL[(size_t)ng * HC + col] = __float2bfloat16(acc[i][c]);
            } else {
                float v = acc[i][c] + (add_bias ? bias[col - HC] : 0.0f);
                outR[(size_t)ng * HC + (col - HC)] = v;
            }
        }
    }
}

// ---------------- launch ----------------

extern "C" void kernel_launch(void* const* d_in, const int* in_sizes, int n_in,
                              void* d_out, int out_size, void* d_ws, size_t ws_size,
                              hipStream_t stream) {
    const float* x   = (const float*)d_in[0];
    const float* Wl1 = (const float*)d_in[1];
    const float* Wr1 = (const float*)d_in[2];
    const float* b1  = (const float*)d_in[3];
    const float* Wl2 = (const float*)d_in[4];
    const float* Wr2 = (const float*)d_in[5];
    const float* b2  = (const float*)d_in[6];
    const int* edge_src = (const int*)d_in[7];
    const int* edge_dst = (const int*)d_in[8];
    float* out = (float*)d_out;

    const int N = in_sizes[0] / 64;
    const int E = in_sizes[7];
    const int NBUCK = (N + (1 << BK_SHIFT) - 1) >> BK_SHIFT;   // 98
    size_t buf_bytes = (size_t)N * 64 * 4;
    int cap = E / NBUCK + E / (2 * NBUCK) + 1024;              // mean + 50% + slack
    int cap_max = (int)(buf_bytes / ((size_t)NBUCK * 4));
    if (cap > cap_max) cap = cap_max;

    size_t off = 0;
    auto carve = [&](size_t bytes) -> void* {
        void* p = (char*)d_ws + off;
        off = (off + bytes + 255) & ~(size_t)255;
        return p;
    };
    int*          row_ptr = (int*)carve((size_t)(N + 1) * 4);
    int*          bcursor = (int*)carve((size_t)NBUCK * 4);
    float*        dis     = (float*)carve((size_t)N * 4);
    float*        cnt_inv = (float*)carve((size_t)N * 4);
    int*          csr_src = (int*)carve((size_t)E * 4);
    char*         bufA    = (char*)carve(buf_bytes);
    char*         bufB    = (char*)carve(buf_bytes);
    float*        bufC    = (float*)carve(buf_bytes);          // temp / r1 / r2
    unsigned int* temp    = (unsigned int*)bufC;               // dead before r1 written
    (void)ws_size;

    // bf16 sub-buffers (sequenced so nothing live overlaps):
    unsigned short* xb  = (unsigned short*)bufA;                         // x bf16
    unsigned short* p0b = (unsigned short*)(bufA + buf_bytes / 2);       // p0 bf16
    unsigned short* hb  = (unsigned short*)bufB;                         // h bf16
    unsigned short* t1b = (unsigned short*)bufA;                         // t1 bf16 (xb dead)
    unsigned short* h1b = (unsigned short*)bufB;                         // h1 bf16 (hb dead)
    unsigned short* t2b = (unsigned short*)(bufA + buf_bytes / 2);       // t2 bf16 (p0b dead)

    const int nb_node = (N + 3) / 4;
    const int nb_gemm = (N + 63) / 64;
    const int n4 = N * 64 / 4;

    // CSR build
    init_bcursor_kernel<<<(NBUCK + 255) / 256, 256, 0, stream>>>(bcursor, NBUCK, cap);
    partition_kernel<<<256, 256, 0, stream>>>(edge_src, edge_dst, bcursor, temp, E, NBUCK, cap);
    bucket_csr_kernel<<<NBUCK, 256, 0, stream>>>(temp, bcursor, row_ptr, dis, cnt_inv,
                                                 csr_src, N, cap, NBUCK, E);

    // x -> bf16
    f2bf_kernel<<<(n4 + 255) / 256, 256, 0, stream>>>((const float4*)x, (ushort4*)xb, n4);
    // KProp x2: p0 = S x ; h = S p0   (bf16 rows, fp32 accumulate)
    prop4bf_kernel<1><<<nb_node, 256, 0, stream>>>((const ushort4*)xb, (ushort4*)p0b,
                                                   row_ptr, csr_src, dis, N);
    prop4bf_kernel<2><<<nb_node, 256, 0, stream>>>((const ushort4*)p0b, (ushort4*)hb,
                                                   row_ptr, csr_src, dis, N);
    // [t1(bf16)|r1(fp32)] = h @ [Wl1|Wr1]
    gemm_kernel<128, 8><<<nb_gemm, 256, 0, stream>>>(hb, Wl1, Wr1, nullptr,
                                                     (__hip_bfloat16*)t1b, bufC, N, 0);
    // h1 = selu(mean(t1) + r1 + b1) -> bf16
    prop_mean_bf_kernel<<<nb_node, 256, 0, stream>>>((const ushort4*)t1b, (ushort4*)h1b,
                                                     row_ptr, csr_src, cnt_inv,
                                                     (const float4*)bufC, (const float4*)b1, N);
    // [t2(bf16)|r2+b2(fp32)] = h1 @ [Wl2|Wr2]
    gemm_kernel<80, 5><<<nb_gemm, 256, 0, stream>>>(h1b, Wl2, Wr2, b2,
                                                    (__hip_bfloat16*)t2b, bufC, N, 1);
    // out = softmax(mean(t2) + r2)
    prop_softmax_bf_kernel<<<nb_node, 256, 0, stream>>>((const ushort4*)t2b, out, row_ptr,
                                                        csr_src, cnt_inv, bufC, N);
}

// Round 2
// 368.109 us; speedup vs baseline: 1.0815x; 1.0674x over previous
//
#include <hip/hip_runtime.h>
#include <hip/hip_bf16.h>
#include <math.h>

// Node classifier: KProp(K=2, gcn_norm) -> SAGEConv(64->64)+selu -> SAGEConv(64->40) -> softmax
// N=100000, E=1600000, D=H=64, C=40.
//
// R14 = R13 with both GEMMs moved from fp32 VALU to bf16 MFMA (16x16x32):
//   - block = 64 nodes x OC cols, 4 waves, wave = 16-row band x all cols
//   - weights fp32 -> split bf16 hi+res, two MFMAs per k-step (fp32-precise W)
//   - LDS A/B tiles XOR-swizzled on 16B chunk index (kills stride-128B conflicts)
//   - C/D frag mapping: col = lane&15, row = (lane>>4)*4 + reg

#define RFL(x) __builtin_amdgcn_readfirstlane(x)
#define BK_SHIFT 10        // coarse bucket = dst>>10 (1024 nodes)
#define MAXBUCK 256

typedef short bf16x8 __attribute__((ext_vector_type(8)));
typedef float f32x4 __attribute__((ext_vector_type(4)));
typedef unsigned short ushort8v __attribute__((ext_vector_type(8)));

__device__ __forceinline__ float bf2f(unsigned short u) {
    return __uint_as_float((unsigned)u << 16);
}
__device__ __forceinline__ unsigned short f2bf(float f) {
    __hip_bfloat16 b = __float2bfloat16(f);   // RTN
    return *reinterpret_cast<unsigned short*>(&b);
}

// ---------------- CSR build ----------------

__global__ void init_bcursor_kernel(int* __restrict__ bcursor, int nbuck, int cap) {
    int i = blockIdx.x * blockDim.x + threadIdx.x;
    if (i < nbuck) bcursor[i] = i * cap;
}

// Phase 1: block-private coarse bucket partition; packed u32 (src<<10 | dst&1023).
__global__ __launch_bounds__(256) void partition_kernel(const int* __restrict__ src,
                                                        const int* __restrict__ dst,
                                                        int* __restrict__ bcursor,
                                                        unsigned int* __restrict__ temp,
                                                        int e, int nbuck, int cap) {
    __shared__ int bc[MAXBUCK];
    int t = threadIdx.x;
    int chunk = (e + gridDim.x - 1) / gridDim.x;
    int base = blockIdx.x * chunk;
    int cnt = e - base;
    if (cnt > chunk) cnt = chunk;
    if (cnt < 0) cnt = 0;
    for (int j = t; j < nbuck; j += 256) bc[j] = 0;
    __syncthreads();
    for (int i = t; i < cnt; i += 256) {
        int d = dst[base + i];
        atomicAdd(&bc[d >> BK_SHIFT], 1);
    }
    __syncthreads();
    for (int j = t; j < nbuck; j += 256) {
        int c = bc[j];
        bc[j] = (c > 0) ? atomicAdd(&bcursor[j], c) : 0;
    }
    __syncthreads();
    for (int i = t; i < cnt; i += 256) {
        int s = src[base + i];
        int d = dst[base + i];
        int bk = d >> BK_SHIFT;
        int p = atomicAdd(&bc[bk], 1);
        if (p < (bk + 1) * cap) temp[p] = ((unsigned int)s << BK_SHIFT) | (unsigned int)(d & 1023);
    }
}

// Phase 2: per-bucket counting sort by node_local + deg/dis/cnt_inv/row_ptr.
__global__ __launch_bounds__(256) void bucket_csr_kernel(const unsigned int* __restrict__ temp,
                                                         const int* __restrict__ bcursor,
                                                         int* __restrict__ row_ptr,
                                                         float* __restrict__ dis,
                                                         float* __restrict__ cnt_inv,
                                                         int* __restrict__ csr_src,
                                                         int n, int cap, int nbuck, int e) {
    __shared__ int cnt3[1024];
    __shared__ int part[256];
    int b = blockIdx.x;
    int t = threadIdx.x;
    int nbeg = b << BK_SHIFT;
    int cj = 0;
    if (t < nbuck) {
        cj = bcursor[t] - t * cap;
        if (cj > cap) cj = cap;
    }
    part[t] = cj;
    __syncthreads();
    for (int off = 1; off < 256; off <<= 1) {
        int u = (t >= off) ? part[t - off] : 0;
        __syncthreads();
        part[t] += u;
        __syncthreads();
    }
    int cntb = bcursor[b] - b * cap;
    if (cntb > cap) cntb = cap;
    int bbase = part[b] - cntb;
    __syncthreads();
    for (int i = t; i < 1024; i += 256) cnt3[i] = 0;
    __syncthreads();
    const unsigned int* tb = temp + (size_t)b * cap;
    for (int i = t; i < cntb; i += 256) {
        atomicAdd(&cnt3[tb[i] & 1023u], 1);
    }
    __syncthreads();
    int d0 = cnt3[t * 4 + 0], d1 = cnt3[t * 4 + 1], d2 = cnt3[t * 4 + 2], d3 = cnt3[t * 4 + 3];
    int run = d0 + d1 + d2 + d3;
    int dd[4] = {d0, d1, d2, d3};
#pragma unroll
    for (int k = 0; k < 4; ++k) {
        int node = nbeg + t * 4 + k;
        if (node < n) {
            float fd = (float)dd[k];
            dis[node] = (dd[k] > 0) ? rsqrtf(fd) : 0.0f;
            cnt_inv[node] = 1.0f / fmaxf(fd, 1.0f);
        }
    }
    __syncthreads();
    part[t] = run;
    __syncthreads();
    for (int off = 1; off < 256; off <<= 1) {
        int u = (t >= off) ? part[t - off] : 0;
        __syncthreads();
        part[t] += u;
        __syncthreads();
    }
    int ex = part[t] - run;
    int oo[4];
    oo[0] = ex; oo[1] = ex + d0; oo[2] = ex + d0 + d1; oo[3] = ex + d0 + d1 + d2;
#pragma unroll
    for (int k = 0; k < 4; ++k) {
        cnt3[t * 4 + k] = oo[k];
        int node = nbeg + t * 4 + k;
        if (node < n) row_ptr[node] = bbase + oo[k];
    }
    if (b == nbuck - 1 && t == 0) row_ptr[n] = e;
    __syncthreads();
    for (int i = t; i < cntb; i += 256) {
        unsigned int ed = tb[i];
        int pos = atomicAdd(&cnt3[ed & 1023u], 1);
        csr_src[bbase + pos] = (int)(ed >> BK_SHIFT);
    }
}

// ---------------- fp32 -> bf16 convert ----------------
__global__ void f2bf_kernel(const float4* __restrict__ in, ushort4* __restrict__ out, int n4) {
    int i = blockIdx.x * blockDim.x + threadIdx.x;
    if (i < n4) {
        float4 v = in[i];
        ushort4 u;
        u.x = f2bf(v.x); u.y = f2bf(v.y); u.z = f2bf(v.z); u.w = f2bf(v.w);
        out[i] = u;
    }
}

// ---------------- KProp propagation over bf16 rows (128B), bf16 out ----------------
// Wave per node. lane = g*16 + l: edge slot g (0..3), feature quad l (0..15).
template <int TAG>
__global__ __launch_bounds__(256) void prop4bf_kernel(const ushort4* __restrict__ in4u,
                                                      ushort4* __restrict__ out4u,
                                                      const int* __restrict__ row_ptr,
                                                      const int* __restrict__ csr_src,
                                                      const float* __restrict__ dis,
                                                      int n) {
    int lane = threadIdx.x & 63;
    int g = lane >> 4;
    int l = lane & 15;
    int node = RFL(blockIdx.x * 4 + (threadIdx.x >> 6));
    if (node >= n) return;
    int beg = row_ptr[node];
    int end = row_ptr[node + 1];
    float4 acc = make_float4(0.f, 0.f, 0.f, 0.f);
    int j = beg;
    for (; j + 16 <= end; j += 16) {
        int s[4];
        ushort4 u[4];
        float w[4];
#pragma unroll
        for (int q = 0; q < 4; ++q) s[q] = csr_src[j + q * 4 + g];
#pragma unroll
        for (int q = 0; q < 4; ++q) u[q] = in4u[(size_t)s[q] * 16 + l];
#pragma unroll
        for (int q = 0; q < 4; ++q) w[q] = dis[s[q]];
#pragma unroll
        for (int q = 0; q < 4; ++q) {
            acc.x += w[q] * bf2f(u[q].x);
            acc.y += w[q] * bf2f(u[q].y);
            acc.z += w[q] * bf2f(u[q].z);
            acc.w += w[q] * bf2f(u[q].w);
        }
    }
    for (; j + 8 <= end; j += 8) {
        int s[2];
        ushort4 u[2];
        float w[2];
#pragma unroll
        for (int q = 0; q < 2; ++q) s[q] = csr_src[j + q * 4 + g];
#pragma unroll
        for (int q = 0; q < 2; ++q) u[q] = in4u[(size_t)s[q] * 16 + l];
#pragma unroll
        for (int q = 0; q < 2; ++q) w[q] = dis[s[q]];
#pragma unroll
        for (int q = 0; q < 2; ++q) {
            acc.x += w[q] * bf2f(u[q].x);
            acc.y += w[q] * bf2f(u[q].y);
            acc.z += w[q] * bf2f(u[q].z);
            acc.w += w[q] * bf2f(u[q].w);
        }
    }
    for (; j < end; j += 4) {
        int idx = j + g;
        bool valid = idx < end;
        int s = csr_src[valid ? idx : (end - 1)];
        float w = valid ? dis[s] : 0.0f;
        ushort4 u = in4u[(size_t)s * 16 + l];
        acc.x += w * bf2f(u.x);
        acc.y += w * bf2f(u.y);
        acc.z += w * bf2f(u.z);
        acc.w += w * bf2f(u.w);
    }
    acc.x += __shfl_xor(acc.x, 16); acc.x += __shfl_xor(acc.x, 32);
    acc.y += __shfl_xor(acc.y, 16); acc.y += __shfl_xor(acc.y, 32);
    acc.z += __shfl_xor(acc.z, 16); acc.z += __shfl_xor(acc.z, 32);
    acc.w += __shfl_xor(acc.w, 16); acc.w += __shfl_xor(acc.w, 32);
    if (g == 0) {
        float sc = dis[node];
        ushort4 o;
        o.x = f2bf(acc.x * sc);
        o.y = f2bf(acc.y * sc);
        o.z = f2bf(acc.z * sc);
        o.w = f2bf(acc.w * sc);
        out4u[(size_t)node * 16 + l] = o;
    }
}

// ---------------- mean-agg over bf16 t1 + selu epilogue, bf16 out ----------------
__global__ __launch_bounds__(256) void prop_mean_bf_kernel(const ushort4* __restrict__ in4u,
                                                           ushort4* __restrict__ out4u,
                                                           const int* __restrict__ row_ptr,
                                                           const int* __restrict__ csr_src,
                                                           const float* __restrict__ cnt_inv,
                                                           const float4* __restrict__ r4,
                                                           const float4* __restrict__ b4,
                                                           int n) {
    int lane = threadIdx.x & 63;
    int g = lane >> 4;
    int l = lane & 15;
    int node = RFL(blockIdx.x * 4 + (threadIdx.x >> 6));
    if (node >= n) return;
    int beg = row_ptr[node];
    int end = row_ptr[node + 1];
    float4 acc = make_float4(0.f, 0.f, 0.f, 0.f);
    int j = beg;
    for (; j + 16 <= end; j += 16) {
        int s[4];
        ushort4 u[4];
#pragma unroll
        for (int q = 0; q < 4; ++q) s[q] = csr_src[j + q * 4 + g];
#pragma unroll
        for (int q = 0; q < 4; ++q) u[q] = in4u[(size_t)s[q] * 16 + l];
#pragma unroll
        for (int q = 0; q < 4; ++q) {
            acc.x += bf2f(u[q].x);
            acc.y += bf2f(u[q].y);
            acc.z += bf2f(u[q].z);
            acc.w += bf2f(u[q].w);
        }
    }
    for (; j + 8 <= end; j += 8) {
        int s[2];
        ushort4 u[2];
#pragma unroll
        for (int q = 0; q < 2; ++q) s[q] = csr_src[j + q * 4 + g];
#pragma unroll
        for (int q = 0; q < 2; ++q) u[q] = in4u[(size_t)s[q] * 16 + l];
#pragma unroll
        for (int q = 0; q < 2; ++q) {
            acc.x += bf2f(u[q].x);
            acc.y += bf2f(u[q].y);
            acc.z += bf2f(u[q].z);
            acc.w += bf2f(u[q].w);
        }
    }
    for (; j < end; j += 4) {
        int idx = j + g;
        bool valid = idx < end;
        int s = csr_src[valid ? idx : (end - 1)];
        float w = valid ? 1.0f : 0.0f;
        ushort4 u = in4u[(size_t)s * 16 + l];
        acc.x += w * bf2f(u.x);
        acc.y += w * bf2f(u.y);
        acc.z += w * bf2f(u.z);
        acc.w += w * bf2f(u.w);
    }
    acc.x += __shfl_xor(acc.x, 16); acc.x += __shfl_xor(acc.x, 32);
    acc.y += __shfl_xor(acc.y, 16); acc.y += __shfl_xor(acc.y, 32);
    acc.z += __shfl_xor(acc.z, 16); acc.z += __shfl_xor(acc.z, 32);
    acc.w += __shfl_xor(acc.w, 16); acc.w += __shfl_xor(acc.w, 32);
    if (g == 0) {
        float sc = cnt_inv[node];
        float4 ra = r4[(size_t)node * 16 + l];
        float4 bb = b4[l];
        const float scale = 1.0507009873554805f;
        const float alpha = 1.6732632423543772f;
        float t0 = acc.x * sc + ra.x + bb.x;
        float t1 = acc.y * sc + ra.y + bb.y;
        float t2 = acc.z * sc + ra.z + bb.z;
        float t3 = acc.w * sc + ra.w + bb.w;
        t0 = scale * (t0 > 0.0f ? t0 : alpha * expm1f(t0));
        t1 = scale * (t1 > 0.0f ? t1 : alpha * expm1f(t1));
        t2 = scale * (t2 > 0.0f ? t2 : alpha * expm1f(t2));
        t3 = scale * (t3 > 0.0f ? t3 : alpha * expm1f(t3));
        ushort4 o;
        o.x = f2bf(t0); o.y = f2bf(t1); o.z = f2bf(t2); o.w = f2bf(t3);
        out4u[(size_t)node * 16 + l] = o;
    }
}

// ---------------- 40-wide softmax prop over bf16 t2 (ushort4 gathers) ----------------
// Wave per node. lane = g*16 + l: edge slot g (0..3), feature quad l (0..15, active l<10).
// t2 row = 40 bf16 = 10 ushort4 = 80B, read exactly.
__global__ __launch_bounds__(256) void prop_softmax_bf_kernel(const ushort4* __restrict__ in4u,
                                                              float* __restrict__ out,
                                                              const int* __restrict__ row_ptr,
                                                              const int* __restrict__ csr_src,
                                                              const float* __restrict__ cnt_inv,
                                                              const float* __restrict__ r_add,
                                                              int n) {
    int lane = threadIdx.x & 63;
    int g = lane >> 4;
    int l = lane & 15;
    bool act = l < 10;
    int node = RFL(blockIdx.x * 4 + (threadIdx.x >> 6));
    if (node >= n) return;
    int beg = row_ptr[node];
    int end = row_ptr[node + 1];
    float4 acc = make_float4(0.f, 0.f, 0.f, 0.f);
    const ushort4 uz = make_ushort4(0, 0, 0, 0);
    int j = beg;
    for (; j + 16 <= end; j += 16) {
        int s[4];
        ushort4 u[4] = {uz, uz, uz, uz};
#pragma unroll
        for (int q = 0; q < 4; ++q) s[q] = csr_src[j + q * 4 + g];
        if (act) {
#pragma unroll
            for (int q = 0; q < 4; ++q) u[q] = in4u[(size_t)s[q] * 10 + l];
        }
#pragma unroll
        for (int q = 0; q < 4; ++q) {
            acc.x += bf2f(u[q].x);
            acc.y += bf2f(u[q].y);
            acc.z += bf2f(u[q].z);
            acc.w += bf2f(u[q].w);
        }
    }
    for (; j + 8 <= end; j += 8) {
        int s[2];
        ushort4 u[2] = {uz, uz};
#pragma unroll
        for (int q = 0; q < 2; ++q) s[q] = csr_src[j + q * 4 + g];
        if (act) {
#pragma unroll
            for (int q = 0; q < 2; ++q) u[q] = in4u[(size_t)s[q] * 10 + l];
        }
#pragma unroll
        for (int q = 0; q < 2; ++q) {
            acc.x += bf2f(u[q].x);
            acc.y += bf2f(u[q].y);
            acc.z += bf2f(u[q].z);
            acc.w += bf2f(u[q].w);
        }
    }
    for (; j < end; j += 4) {
        int idx = j + g;
        bool valid = idx < end;
        int s = csr_src[valid ? idx : (end - 1)];
        if (act) {
            ushort4 u = in4u[(size_t)s * 10 + l];
            float w = valid ? 1.0f : 0.0f;
            acc.x += w * bf2f(u.x);
            acc.y += w * bf2f(u.y);
            acc.z += w * bf2f(u.z);
            acc.w += w * bf2f(u.w);
        }
    }
    acc.x += __shfl_xor(acc.x, 16); acc.x += __shfl_xor(acc.x, 32);
    acc.y += __shfl_xor(acc.y, 16); acc.y += __shfl_xor(acc.y, 32);
    acc.z += __shfl_xor(acc.z, 16); acc.z += __shfl_xor(acc.z, 32);
    acc.w += __shfl_xor(acc.w, 16); acc.w += __shfl_xor(acc.w, 32);
    if (g == 0) {
        float sc = cnt_inv[node];
        float4 ra = act ? reinterpret_cast<const float4*>(r_add)[(size_t)node * 10 + l]
                        : make_float4(0.f, 0.f, 0.f, 0.f);
        float t0 = acc.x * sc + ra.x;
        float t1 = acc.y * sc + ra.y;
        float t2 = acc.z * sc + ra.z;
        float t3 = acc.w * sc + ra.w;
        float m = act ? fmaxf(fmaxf(t0, t1), fmaxf(t2, t3)) : -INFINITY;
        m = fmaxf(m, __shfl_xor(m, 1));
        m = fmaxf(m, __shfl_xor(m, 2));
        m = fmaxf(m, __shfl_xor(m, 4));
        m = fmaxf(m, __shfl_xor(m, 8));
        float e0 = act ? __expf(t0 - m) : 0.0f;
        float e1 = act ? __expf(t1 - m) : 0.0f;
        float e2 = act ? __expf(t2 - m) : 0.0f;
        float e3 = act ? __expf(t3 - m) : 0.0f;
        float s = e0 + e1 + e2 + e3;
        s += __shfl_xor(s, 1);
        s += __shfl_xor(s, 2);
        s += __shfl_xor(s, 4);
        s += __shfl_xor(s, 8);
        if (act) {
            float inv = 1.0f / s;
            float4 o;
            o.x = e0 * inv; o.y = e1 * inv; o.z = e2 * inv; o.w = e3 * inv;
            reinterpret_cast<float4*>(out)[(size_t)node * 10 + l] = o;
        }
    }
}

// ---------------- MFMA GEMM: [outL(bf16)|outR(fp32)] = in_bf16(N x 64) @ [Wl|Wr] ----------------
// Block = 64 nodes x OC cols, 4 waves; wave = 16-node band x all OC cols.
// Weights fp32 split into bf16 hi + bf16 residual; both MFMA'd into the same fp32 acc.
// LDS tiles [row][k] bf16, XOR-swizzled: 16B-chunk index kb ^= (row&7).
template <int OC>
__global__ __launch_bounds__(256) void gemm_mfma_kernel(const unsigned short* __restrict__ in,
                                                        const float* __restrict__ Wl,
                                                        const float* __restrict__ Wr,
                                                        const float* __restrict__ bias,
                                                        __hip_bfloat16* __restrict__ outL,
                                                        float* __restrict__ outR,
                                                        int n, int add_bias) {
    constexpr int HC = OC / 2;
    constexpr int NF = OC / 16;          // n-frags per wave
    __shared__ unsigned short sA[64 * 64];        // [m][k] swizzled
    __shared__ unsigned short sBh[OC * 64];       // [c][k] swizzled, hi
    __shared__ unsigned short sBr[OC * 64];       // [c][k] swizzled, residual
    int t = threadIdx.x;
    int blk = blockIdx.x;

    // Stage A: 64 nodes x 64 k bf16, 16B chunks. idx -> m = idx>>3, kb = idx&7.
#pragma unroll
    for (int i = 0; i < 2; ++i) {
        int idx = i * 256 + t;
        int m = idx >> 3;
        int kb = idx & 7;
        int node = blk * 64 + m;
        if (node >= n) node = n - 1;
        ushort8v v = *reinterpret_cast<const ushort8v*>(in + (size_t)node * 64 + kb * 8);
        *reinterpret_cast<ushort8v*>(&sA[m * 64 + ((kb ^ (m & 7)) << 3)]) = v;
    }
    // Stage B: [Wl|Wr] fp32 64k x OC -> bf16 hi/res, transposed to [c][k].
    for (int idx = t; idx < 64 * OC; idx += 256) {
        int k = idx / OC;
        int c = idx - k * OC;
        float v = (c < HC) ? Wl[k * HC + c] : Wr[k * HC + (c - HC)];
        unsigned short hi = f2bf(v);
        unsigned short re = f2bf(v - bf2f(hi));
        int pos = c * 64 + (((k >> 3) ^ (c & 7)) << 3) + (k & 7);
        sBh[pos] = hi;
        sBr[pos] = re;
    }
    __syncthreads();

    int w = t >> 6;          // wave id: m-band [w*16, w*16+16)
    int lane = t & 63;
    int r = lane & 15;
    int q = lane >> 4;       // k-block within MFMA
    int m = w * 16 + r;      // A row for input frags
    // A frags: k-chunks (s*4+q) for MFMA k-step s
    bf16x8 A0 = *reinterpret_cast<const bf16x8*>(&sA[m * 64 + (((0 + q) ^ (r & 7)) << 3)]);
    bf16x8 A1 = *reinterpret_cast<const bf16x8*>(&sA[m * 64 + (((4 + q) ^ (r & 7)) << 3)]);

    f32x4 acc[NF];
#pragma unroll
    for (int c = 0; c < NF; ++c) acc[c] = (f32x4)(0.0f);

#pragma unroll
    for (int c = 0; c < NF; ++c) {
        int cb = c * 16 + r;
        bf16x8 B0 = *reinterpret_cast<const bf16x8*>(&sBh[cb * 64 + (((0 + q) ^ (r & 7)) << 3)]);
        bf16x8 B1 = *reinterpret_cast<const bf16x8*>(&sBh[cb * 64 + (((4 + q) ^ (r & 7)) << 3)]);
        bf16x8 R0 = *reinterpret_cast<const bf16x8*>(&sBr[cb * 64 + (((0 + q) ^ (r & 7)) << 3)]);
        bf16x8 R1 = *reinterpret_cast<const bf16x8*>(&sBr[cb * 64 + (((4 + q) ^ (r & 7)) << 3)]);
        acc[c] = __builtin_amdgcn_mfma_f32_16x16x32_bf16(A0, B0, acc[c], 0, 0, 0);
        acc[c] = __builtin_amdgcn_mfma_f32_16x16x32_bf16(A1, B1, acc[c], 0, 0, 0);
        acc[c] = __builtin_amdgcn_mfma_f32_16x16x32_bf16(A0, R0, acc[c], 0, 0, 0);
        acc[c] = __builtin_amdgcn_mfma_f32_16x16x32_bf16(A1, R1, acc[c], 0, 0, 0);
    }

    // Epilogue: C/D frag: col = c*16 + (lane&15), row = (lane>>4)*4 + j (within wave's band).
#pragma unroll
    for (int c = 0; c < NF; ++c) {
        int col = c * 16 + r;
#pragma unroll
        for (int j = 0; j < 4; ++j) {
            int node = blk * 64 + w * 16 + q * 4 + j;
            if (node < n) {
                float v = acc[c][j];
                if (col < HC) {
                    outL[(size_t)node * HC + col] = __float2bfloat16(v);
                } else {
                    outR[(size_t)node * HC + (col - HC)] = v + (add_bias ? bias[col - HC] : 0.0f);
                }
            }
        }
    }
}

// ---------------- launch ----------------

extern "C" void kernel_launch(void* const* d_in, const int* in_sizes, int n_in,
                              void* d_out, int out_size, void* d_ws, size_t ws_size,
                              hipStream_t stream) {
    const float* x   = (const float*)d_in[0];
    const float* Wl1 = (const float*)d_in[1];
    const float* Wr1 = (const float*)d_in[2];
    const float* b1  = (const float*)d_in[3];
    const float* Wl2 = (const float*)d_in[4];
    const float* Wr2 = (const float*)d_in[5];
    const float* b2  = (const float*)d_in[6];
    const int* edge_src = (const int*)d_in[7];
    const int* edge_dst = (const int*)d_in[8];
    float* out = (float*)d_out;

    const int N = in_sizes[0] / 64;
    const int E = in_sizes[7];
    const int NBUCK = (N + (1 << BK_SHIFT) - 1) >> BK_SHIFT;   // 98
    size_t buf_bytes = (size_t)N * 64 * 4;
    int cap = E / NBUCK + E / (2 * NBUCK) + 1024;              // mean + 50% + slack
    int cap_max = (int)(buf_bytes / ((size_t)NBUCK * 4));
    if (cap > cap_max) cap = cap_max;

    size_t off = 0;
    auto carve = [&](size_t bytes) -> void* {
        void* p = (char*)d_ws + off;
        off = (off + bytes + 255) & ~(size_t)255;
        return p;
    };
    int*          row_ptr = (int*)carve((size_t)(N + 1) * 4);
    int*          bcursor = (int*)carve((size_t)NBUCK * 4);
    float*        dis     = (float*)carve((size_t)N * 4);
    float*        cnt_inv = (float*)carve((size_t)N * 4);
    int*          csr_src = (int*)carve((size_t)E * 4);
    char*         bufA    = (char*)carve(buf_bytes);
    char*         bufB    = (char*)carve(buf_bytes);
    float*        bufC    = (float*)carve(buf_bytes);          // temp / r1 / r2
    unsigned int* temp    = (unsigned int*)bufC;               // dead before r1 written
    (void)ws_size;

    // bf16 sub-buffers (sequenced so nothing live overlaps):
    unsigned short* xb  = (unsigned short*)bufA;                         // x bf16
    unsigned short* p0b = (unsigned short*)(bufA + buf_bytes / 2);       // p0 bf16
    unsigned short* hb  = (unsigned short*)bufB;                         // h bf16
    unsigned short* t1b = (unsigned short*)bufA;                         // t1 bf16 (xb dead)
    unsigned short* h1b = (unsigned short*)bufB;                         // h1 bf16 (hb dead)
    unsigned short* t2b = (unsigned short*)(bufA + buf_bytes / 2);       // t2 bf16 (p0b dead)

    const int nb_node = (N + 3) / 4;
    const int nb_gemm = (N + 63) / 64;
    const int n4 = N * 64 / 4;

    // CSR build
    init_bcursor_kernel<<<(NBUCK + 255) / 256, 256, 0, stream>>>(bcursor, NBUCK, cap);
    partition_kernel<<<256, 256, 0, stream>>>(edge_src, edge_dst, bcursor, temp, E, NBUCK, cap);
    bucket_csr_kernel<<<NBUCK, 256, 0, stream>>>(temp, bcursor, row_ptr, dis, cnt_inv,
                                                 csr_src, N, cap, NBUCK, E);

    // x -> bf16
    f2bf_kernel<<<(n4 + 255) / 256, 256, 0, stream>>>((const float4*)x, (ushort4*)xb, n4);
    // KProp x2: p0 = S x ; h = S p0   (bf16 rows, fp32 accumulate)
    prop4bf_kernel<1><<<nb_node, 256, 0, stream>>>((const ushort4*)xb, (ushort4*)p0b,
                                                   row_ptr, csr_src, dis, N);
    prop4bf_kernel<2><<<nb_node, 256, 0, stream>>>((const ushort4*)p0b, (ushort4*)hb,
                                                   row_ptr, csr_src, dis, N);
    // [t1(bf16)|r1(fp32)] = h @ [Wl1|Wr1]  (MFMA)
    gemm_mfma_kernel<128><<<nb_gemm, 256, 0, stream>>>(hb, Wl1, Wr1, nullptr,
                                                       (__hip_bfloat16*)t1b, bufC, N, 0);
    // h1 = selu(mean(t1) + r1 + b1) -> bf16
    prop_mean_bf_kernel<<<nb_node, 256, 0, stream>>>((const ushort4*)t1b, (ushort4*)h1b,
                                                     row_ptr, csr_src, cnt_inv,
                                                     (const float4*)bufC, (const float4*)b1, N);
    // [t2(bf16)|r2+b2(fp32)] = h1 @ [Wl2|Wr2]  (MFMA)
    gemm_mfma_kernel<80><<<nb_gemm, 256, 0, stream>>>(h1b, Wl2, Wr2, b2,
                                                      (__hip_bfloat16*)t2b, bufC, N, 1);
    // out = softmax(mean(t2) + r2)
    prop_softmax_bf_kernel<<<nb_node, 256, 0, stream>>>((const ushort4*)t2b, out, row_ptr,
                                                        csr_src, cnt_inv, bufC, N);
}